// Round 4
// 16750.253 us; speedup vs baseline: 1.3634x; 1.3634x over previous
//
#include <hip/hip_runtime.h>
#include <hip/hip_bf16.h>
#include <hip/hip_cooperative_groups.h>

namespace cg = cooperative_groups;

#define B_  32
#define T_  64
#define S_  64
#define E_  256
#define H_  512
#define A_  512
#define DV_ 32000
#define H4_ 2048
#define NCAT_ 4608   /* W1T(512) + Wh0T(2048) + Wh1T(2048) rows */

typedef __attribute__((ext_vector_type(8))) short short8;
typedef __attribute__((ext_vector_type(4))) float floatx4;

__device__ __forceinline__ float fast_sigmoid(float x) {
    return 1.0f / (1.0f + __expf(-x));
}
__device__ __forceinline__ float fast_tanh(float x) {
    x = fminf(9.0f, fmaxf(-9.0f, x));
    float e = __expf(2.0f * x);
    return (e - 1.0f) / (e + 1.0f);
}
__device__ __forceinline__ unsigned short f2bf(float f) {
    union { float f; unsigned u; } v; v.f = f;
    unsigned r = (v.u + 0x7fffu + ((v.u >> 16) & 1u)) >> 16;
    return (unsigned short)r;
}

// ---------------------------------------------------------------------------
// Setup: enc_proj = encoder_output @ W2 + b2   (blocks 0..4095)
//        state init from hidden0/cell0         (blocks 4096..4099)
// ---------------------------------------------------------------------------
__global__ __launch_bounds__(256) void k_setup(
    const float* __restrict__ enc, const float* __restrict__ W2,
    const float* __restrict__ b2, const float* __restrict__ hidden0,
    const float* __restrict__ cell0,
    float* __restrict__ encp, float* __restrict__ h0buf,
    float* __restrict__ h1buf, float* __restrict__ c0, float* __restrict__ c1)
{
    int bid = blockIdx.x, tid = threadIdx.x;
    if (bid < 4096) {
        int eid = bid * 256 + tid;      // 2048 rows x 512 cols
        int r = eid >> 9;
        int n = eid & 511;
        const float* er = enc + (size_t)r * H_;
        float acc = b2[n];
#pragma unroll 4
        for (int k = 0; k < H_; ++k)
            acc = fmaf(er[k], W2[(size_t)k * A_ + n], acc);
        encp[(size_t)r * A_ + n] = acc;
    } else {
        int which = bid - 4096;  // 0..3
        const float* src = (which == 0) ? hidden0
                         : (which == 1) ? hidden0 + B_ * H_
                         : (which == 2) ? cell0
                         : cell0 + B_ * H_;
        float* dst = (which == 0) ? h0buf : (which == 1) ? h1buf
                   : (which == 2) ? c0 : c1;
        for (int i = tid; i < B_ * H_; i += 256) dst[i] = src[i];
    }
}

// ---------------------------------------------------------------------------
// Wd [512,32000] fp32  ->  WdT [32000,512] bf16 (K-contiguous rows)
// ---------------------------------------------------------------------------
__global__ __launch_bounds__(256) void k_wdt(const float* __restrict__ Wd,
                                             unsigned short* __restrict__ WdT)
{
    __shared__ float tle[64 * 65];
    int kb = blockIdx.x & 7, nb = blockIdx.x >> 3;
    int k0 = kb * 64, n0 = nb * 64;
    int tid = threadIdx.x;
    for (int i = 0; i < 16; ++i) {
        int e = tid + 256 * i;
        int kk = e >> 6, nn = e & 63;
        tle[kk * 65 + nn] = Wd[(size_t)(k0 + kk) * DV_ + n0 + nn];
    }
    __syncthreads();
    for (int i = 0; i < 16; ++i) {
        int e = tid + 256 * i;
        int nn = e >> 6, kk = e & 63;
        WdT[(size_t)(n0 + nn) * H_ + k0 + kk] = f2bf(tle[kk * 65 + nn]);
    }
}

// ---------------------------------------------------------------------------
// Generic fp32 transpose: dst[n*K + k] = src[k*N + n]. K,N multiples of 64.
// ---------------------------------------------------------------------------
__global__ __launch_bounds__(256) void k_transpose(const float* __restrict__ src,
                                                   float* __restrict__ dst,
                                                   int K, int N)
{
    __shared__ float tle[64 * 65];
    int nt = N >> 6;
    int nb = blockIdx.x % nt, kb = blockIdx.x / nt;
    int k0 = kb * 64, n0 = nb * 64;
    int tid = threadIdx.x;
    for (int i = 0; i < 16; ++i) {
        int e = tid + 256 * i;
        int kk = e >> 6, nn = e & 63;
        tle[kk * 65 + nn] = src[(size_t)(k0 + kk) * N + n0 + nn];
    }
    __syncthreads();
    for (int i = 0; i < 16; ++i) {
        int e = tid + 256 * i;
        int nn = e >> 6, kk = e & 63;
        dst[(size_t)(n0 + nn) * K + k0 + kk] = tle[kk * 65 + nn];
    }
}

// ---------------------------------------------------------------------------
// Cooperative recurrence kernel (FAST PATH): transposed weights, float4 dots.
// ---------------------------------------------------------------------------
struct DecodeParams {
    const float *x;                 // [B,T,E]
    const float *enc;               // [B,S,H]
    const float *b1, *V, *bV, *bL0, *bL1;
    const float *encp;              // [B,S,A]
    const float *WcatT;             // [4608,512]
    const float *Wx0T;              // [2048,768]
    const float *Wx1T;              // [2048,512]
    float *qg, *p0g, *p1g, *ctx;
    float *h0buf, *h1buf, *c0, *c1;
    unsigned short *h1b;            // [T,B,H] bf16
    float *out_hc;                  // d_out + B*T*DV
};

__global__ __launch_bounds__(256, 2) void k_decode(DecodeParams p)
{
    cg::grid_group grid = cg::this_grid();
    const int bid = blockIdx.x, tid = threadIdx.x;
    const int lane = tid & 63;

    __shared__ float red2[256];
    __shared__ float qs[A_];
    __shared__ float smax[S_];

    for (int t = 0; t < T_; ++t) {
        const int cur = t & 1, nxt = cur ^ 1;
        const float* h0c = p.h0buf + cur * (B_ * H_);
        float*       h0n = p.h0buf + nxt * (B_ * H_);
        const float* h1c = p.h1buf + cur * (B_ * H_);
        float*       h1n = p.h1buf + nxt * (B_ * H_);

        // ---- A1: q = h1@W1+b1 ; p0 = h0@Wh0 ; p1 = h1@Wh1
        {
            int g0 = (bid * 576) >> 8;
            int g1 = ((bid + 1) * 576) >> 8;
            int b = tid >> 3, nl = tid & 7;
            for (int g = g0; g < g1; ++g) {
                const float *src; const float *bias = nullptr; float* dst;
                int n0, N, rbase;
                if (g < 64)       { src = h1c; dst = p.qg;  n0 = g * 8;         N = A_;  bias = p.b1; rbase = 0; }
                else if (g < 320) { src = h0c; dst = p.p0g; n0 = (g - 64) * 8;  N = H4_; rbase = 512; }
                else              { src = h1c; dst = p.p1g; n0 = (g - 320) * 8; N = H4_; rbase = 2560; }
                int n = n0 + nl;
                const float4* w4 = (const float4*)(p.WcatT + ((size_t)(rbase + n) << 9));
                const float4* h4 = (const float4*)(src + (b << 9));
                float ax = 0.f, ay = 0.f, az = 0.f, aw = 0.f;
#pragma unroll 8
                for (int kk = 0; kk < 128; ++kk) {
                    float4 w = w4[kk], h = h4[kk];
                    ax = fmaf(w.x, h.x, ax);
                    ay = fmaf(w.y, h.y, ay);
                    az = fmaf(w.z, h.z, az);
                    aw = fmaf(w.w, h.w, aw);
                }
                float acc = (ax + ay) + (az + aw);
                if (bias) acc += bias[n];
                dst[b * N + n] = acc;
            }
        }
        grid.sync();

        // ---- A2: scores -> softmax -> context
        if (bid < B_) {
            const int b = bid;
            qs[tid] = p.qg[b * A_ + tid];
            qs[tid + 256] = p.qg[b * A_ + tid + 256];
            __syncthreads();
            {
                int s = tid >> 2, pp = tid & 3;
                const float* ep = p.encp + ((size_t)(b * S_ + s)) * A_ + pp * 128;
                const float* qq = qs + pp * 128;
                const float* Vv = p.V + pp * 128;
                float acc = 0.f;
#pragma unroll 4
                for (int a = 0; a < 128; ++a)
                    acc = fmaf(fast_tanh(ep[a] + qq[a]), Vv[a], acc);
                red2[tid] = acc;
            }
            __syncthreads();
            if (tid < 64) {
                float sv = red2[tid * 4] + red2[tid * 4 + 1] +
                           red2[tid * 4 + 2] + red2[tid * 4 + 3] + p.bV[0];
                float m = sv;
                for (int o = 32; o > 0; o >>= 1) m = fmaxf(m, __shfl_xor(m, o));
                float e = __expf(sv - m);
                float sum = e;
                for (int o = 32; o > 0; o >>= 1) sum += __shfl_xor(sum, o);
                smax[tid] = e / sum;
            }
            __syncthreads();
            {
                float a0 = 0.f, a1 = 0.f;
                for (int s2 = 0; s2 < S_; ++s2) {
                    float at = smax[s2];
                    const float* er = p.enc + ((size_t)(b * S_ + s2)) * H_;
                    a0 = fmaf(at, er[tid], a0);
                    a1 = fmaf(at, er[tid + 256], a1);
                }
                p.ctx[b * H_ + tid] = a0;
                p.ctx[b * H_ + tid + 256] = a1;
            }
        }
        grid.sync();

        // ---- B: z0 = p0 + ctx@Wx0[:512] + x_t@Wx0[512:768] + bL0 -> h0,c0
        {
            int b = tid >> 3, jg = tid & 7;
            int j = bid * 2 + (jg & 1), g = jg >> 1;
            int n = j + (g << 9);
            const float4* w4 = (const float4*)(p.Wx0T + (size_t)n * 768);
            const float4* c4 = (const float4*)(p.ctx + (b << 9));
            const float4* x4 = (const float4*)(p.x + ((size_t)b * T_ + t) * E_);
            float ax = 0.f, ay = 0.f, az = 0.f, aw = 0.f;
#pragma unroll 8
            for (int kk = 0; kk < 128; ++kk) {
                float4 w = w4[kk], h = c4[kk];
                ax = fmaf(w.x, h.x, ax);
                ay = fmaf(w.y, h.y, ay);
                az = fmaf(w.z, h.z, az);
                aw = fmaf(w.w, h.w, aw);
            }
#pragma unroll 8
            for (int kk = 0; kk < 64; ++kk) {
                float4 w = w4[128 + kk], h = x4[kk];
                ax = fmaf(w.x, h.x, ax);
                ay = fmaf(w.y, h.y, ay);
                az = fmaf(w.z, h.z, az);
                aw = fmaf(w.w, h.w, aw);
            }
            float acc = p.p0g[b * H4_ + n] + p.bL0[n] + (ax + ay) + (az + aw);
            int lb = lane & ~7, jj = jg & 1;
            float z_f = __shfl(acc, lb + jj + 2);
            float z_g = __shfl(acc, lb + jj + 4);
            float z_o = __shfl(acc, lb + jj + 6);
            if (jg < 2) {
                float ii = fast_sigmoid(acc);
                float ff = fast_sigmoid(z_f);
                float gg = fast_tanh(z_g);
                float oo = fast_sigmoid(z_o);
                float cn = ff * p.c0[b * H_ + j] + ii * gg;
                float hn = oo * fast_tanh(cn);
                p.c0[b * H_ + j] = cn;
                h0n[b * H_ + j] = hn;
            }
        }
        grid.sync();

        // ---- C: z1 = p1 + h0_new@Wx1 + bL1 -> h1,c1 ; store h1 as bf16
        {
            int b = tid >> 3, jg = tid & 7;
            int j = bid * 2 + (jg & 1), g = jg >> 1;
            int n = j + (g << 9);
            const float4* w4 = (const float4*)(p.Wx1T + ((size_t)n << 9));
            const float4* h4 = (const float4*)(h0n + (b << 9));
            float ax = 0.f, ay = 0.f, az = 0.f, aw = 0.f;
#pragma unroll 8
            for (int kk = 0; kk < 128; ++kk) {
                float4 w = w4[kk], h = h4[kk];
                ax = fmaf(w.x, h.x, ax);
                ay = fmaf(w.y, h.y, ay);
                az = fmaf(w.z, h.z, az);
                aw = fmaf(w.w, h.w, aw);
            }
            float acc = p.p1g[b * H4_ + n] + p.bL1[n] + (ax + ay) + (az + aw);
            int lb = lane & ~7, jj = jg & 1;
            float z_f = __shfl(acc, lb + jj + 2);
            float z_g = __shfl(acc, lb + jj + 4);
            float z_o = __shfl(acc, lb + jj + 6);
            if (jg < 2) {
                float ii = fast_sigmoid(acc);
                float ff = fast_sigmoid(z_f);
                float gg = fast_tanh(z_g);
                float oo = fast_sigmoid(z_o);
                float cn = ff * p.c1[b * H_ + j] + ii * gg;
                float hn = oo * fast_tanh(cn);
                p.c1[b * H_ + j] = cn;
                h1n[b * H_ + j] = hn;
                p.h1b[((size_t)t * B_ + b) * H_ + j] = f2bf(hn);
            }
        }
        grid.sync();
    }

    // ---- tail
    {
        int idx = bid * 256 + tid;
        if (idx < B_ * H_) {
            p.out_hc[idx]                 = p.h0buf[idx];
            p.out_hc[B_ * H_ + idx]       = p.h1buf[idx];
            p.out_hc[2 * B_ * H_ + idx]   = p.c0[idx];
            p.out_hc[3 * B_ * H_ + idx]   = p.c1[idx];
        }
    }
}

// ---------------------------------------------------------------------------
// FALLBACK PATH: per-step normal launches, bodies verbatim from the
// verified-passing baseline (original weight layout, no grid.sync).
// ---------------------------------------------------------------------------
struct StepParams {
    const float *x, *enc;
    const float *W1, *b1, *V, *bV;
    const float *Wx0, *Wh0, *bL0, *Wx1, *Wh1, *bL1;
    const float *encp;
    float *qg, *p0g, *p1g, *ctx;
    float *h0buf, *h1buf, *c0, *c1;
    unsigned short *h1b;
    int t;
};

__global__ __launch_bounds__(256) void kA1_fb(StepParams p)
{
    int bid = blockIdx.x, tid = threadIdx.x;
    int cur = p.t & 1;
    const float* h0c = p.h0buf + cur * (B_ * H_);
    const float* h1c = p.h1buf + cur * (B_ * H_);
    int g0 = (bid * 576) >> 8;
    int g1 = ((bid + 1) * 576) >> 8;
    int b = tid >> 3, nl = tid & 7;
    for (int g = g0; g < g1; ++g) {
        const float *src, *W, *bias = nullptr; float* dst;
        int n0, N;
        if (g < 64)       { src = h1c; W = p.W1;  dst = p.qg;  n0 = g * 8;         N = A_;  bias = p.b1; }
        else if (g < 320) { src = h0c; W = p.Wh0; dst = p.p0g; n0 = (g - 64) * 8;  N = H4_; }
        else              { src = h1c; W = p.Wh1; dst = p.p1g; n0 = (g - 320) * 8; N = H4_; }
        int n = n0 + nl;
        const float* sr = src + b * H_;
        float acc = 0.f;
#pragma unroll 4
        for (int k = 0; k < H_; ++k)
            acc = fmaf(sr[k], W[(size_t)k * N + n], acc);
        if (bias) acc += bias[n];
        dst[b * N + n] = acc;
    }
}

__global__ __launch_bounds__(256) void kA2_fb(StepParams p)
{
    int b = blockIdx.x, tid = threadIdx.x;
    __shared__ float red2[256];
    __shared__ float qs[A_];
    __shared__ float smax[S_];
    qs[tid] = p.qg[b * A_ + tid];
    qs[tid + 256] = p.qg[b * A_ + tid + 256];
    __syncthreads();
    {
        int s = tid >> 2, pp = tid & 3;
        const float* ep = p.encp + ((size_t)(b * S_ + s)) * A_ + pp * 128;
        const float* qq = qs + pp * 128;
        const float* Vv = p.V + pp * 128;
        float acc = 0.f;
#pragma unroll 4
        for (int a = 0; a < 128; ++a)
            acc = fmaf(fast_tanh(ep[a] + qq[a]), Vv[a], acc);
        red2[tid] = acc;
    }
    __syncthreads();
    if (tid < 64) {
        float sv = red2[tid * 4] + red2[tid * 4 + 1] +
                   red2[tid * 4 + 2] + red2[tid * 4 + 3] + p.bV[0];
        float m = sv;
        for (int o = 32; o > 0; o >>= 1) m = fmaxf(m, __shfl_xor(m, o));
        float e = __expf(sv - m);
        float sum = e;
        for (int o = 32; o > 0; o >>= 1) sum += __shfl_xor(sum, o);
        smax[tid] = e / sum;
    }
    __syncthreads();
    {
        float a0 = 0.f, a1 = 0.f;
        for (int s2 = 0; s2 < S_; ++s2) {
            float at = smax[s2];
            const float* er = p.enc + ((size_t)(b * S_ + s2)) * H_;
            a0 = fmaf(at, er[tid], a0);
            a1 = fmaf(at, er[tid + 256], a1);
        }
        p.ctx[b * H_ + tid] = a0;
        p.ctx[b * H_ + tid + 256] = a1;
    }
}

__global__ __launch_bounds__(256) void kB_fb(StepParams p)
{
    int bid = blockIdx.x, tid = threadIdx.x;
    int lane = tid & 63;
    int nxt = (p.t & 1) ^ 1;
    float* h0n = p.h0buf + nxt * (B_ * H_);
    int b = tid >> 3, jg = tid & 7;
    int j = bid * 2 + (jg & 1), g = jg >> 1;
    int n = j + (g << 9);
    float acc = p.p0g[b * H4_ + n] + p.bL0[n];
    const float* cr = p.ctx + b * H_;
    const float* xr = p.x + ((size_t)b * T_ + p.t) * E_;
#pragma unroll 4
    for (int k = 0; k < H_; ++k)
        acc = fmaf(cr[k], p.Wx0[(size_t)k * H4_ + n], acc);
#pragma unroll 4
    for (int k = 0; k < E_; ++k)
        acc = fmaf(xr[k], p.Wx0[(size_t)(H_ + k) * H4_ + n], acc);
    int lb = lane & ~7, jj = jg & 1;
    float z_f = __shfl(acc, lb + jj + 2);
    float z_g = __shfl(acc, lb + jj + 4);
    float z_o = __shfl(acc, lb + jj + 6);
    if (jg < 2) {
        float ii = fast_sigmoid(acc);
        float ff = fast_sigmoid(z_f);
        float gg = fast_tanh(z_g);
        float oo = fast_sigmoid(z_o);
        float cn = ff * p.c0[b * H_ + j] + ii * gg;
        float hn = oo * fast_tanh(cn);
        p.c0[b * H_ + j] = cn;
        h0n[b * H_ + j] = hn;
    }
}

__global__ __launch_bounds__(256) void kC_fb(StepParams p)
{
    int bid = blockIdx.x, tid = threadIdx.x;
    int lane = tid & 63;
    int nxt = (p.t & 1) ^ 1;
    const float* h0n = p.h0buf + nxt * (B_ * H_);
    float*       h1n = p.h1buf + nxt * (B_ * H_);
    int b = tid >> 3, jg = tid & 7;
    int j = bid * 2 + (jg & 1), g = jg >> 1;
    int n = j + (g << 9);
    float acc = p.p1g[b * H4_ + n] + p.bL1[n];
    const float* hr = h0n + b * H_;
#pragma unroll 4
    for (int k = 0; k < H_; ++k)
        acc = fmaf(hr[k], p.Wx1[(size_t)k * H4_ + n], acc);
    int lb = lane & ~7, jj = jg & 1;
    float z_f = __shfl(acc, lb + jj + 2);
    float z_g = __shfl(acc, lb + jj + 4);
    float z_o = __shfl(acc, lb + jj + 6);
    if (jg < 2) {
        float ii = fast_sigmoid(acc);
        float ff = fast_sigmoid(z_f);
        float gg = fast_tanh(z_g);
        float oo = fast_sigmoid(z_o);
        float cn = ff * p.c1[b * H_ + j] + ii * gg;
        float hn = oo * fast_tanh(cn);
        p.c1[b * H_ + j] = cn;
        h1n[b * H_ + j] = hn;
        p.h1b[((size_t)p.t * B_ + b) * H_ + j] = f2bf(hn);
    }
}

__global__ __launch_bounds__(256) void k_tail_fb(
    const float* __restrict__ h0buf, const float* __restrict__ h1buf,
    const float* __restrict__ c0, const float* __restrict__ c1,
    float* __restrict__ out_hc)
{
    int idx = blockIdx.x * 256 + threadIdx.x;   // grid 64 -> idx < 16384
    out_hc[idx]               = h0buf[idx];
    out_hc[B_ * H_ + idx]     = h1buf[idx];
    out_hc[2 * B_ * H_ + idx] = c0[idx];
    out_hc[3 * B_ * H_ + idx] = c1[idx];
}

// ---------------------------------------------------------------------------
// Logits: C[m=(t,b), n] = h1b[m,:] . WdT[n,:] + bd[n]  via bf16 MFMA
// ---------------------------------------------------------------------------
__global__ __launch_bounds__(256) void k_logits(
    const unsigned short* __restrict__ Am,   // [2048,512] bf16
    const unsigned short* __restrict__ Bm,   // [32000,512] bf16
    const float* __restrict__ bd,
    float* __restrict__ out)
{
    __shared__ __align__(16) unsigned short As[128 * 72];
    __shared__ __align__(16) unsigned short Bs[128 * 72];
    int tid = threadIdx.x;
    int lane = tid & 63, wv = tid >> 6;
    int mt = blockIdx.x & 15, nt = blockIdx.x >> 4;
    int m0 = mt * 128, n0 = nt * 128;
    int wm = wv >> 1, wn = wv & 1;

    floatx4 acc[4][4];
    for (int i = 0; i < 4; ++i)
        for (int j = 0; j < 4; ++j)
            acc[i][j] = (floatx4){0.f, 0.f, 0.f, 0.f};

    for (int kt = 0; kt < 8; ++kt) {
        int k0 = kt * 64;
        __syncthreads();
        for (int i = 0; i < 4; ++i) {
            int chunk = tid + 256 * i;       // 0..1023
            int row = chunk >> 3, c8 = chunk & 7;
            uint4 va = *(const uint4*)(Am + (size_t)(m0 + row) * H_ + k0 + c8 * 8);
            *(uint4*)(As + row * 72 + c8 * 8) = va;
            uint4 vb = *(const uint4*)(Bm + (size_t)(n0 + row) * H_ + k0 + c8 * 8);
            *(uint4*)(Bs + row * 72 + c8 * 8) = vb;
        }
        __syncthreads();
        int q8 = (lane >> 4) * 8;
        int rl = lane & 15;
        for (int kk = 0; kk < 64; kk += 32) {
            short8 af[4], bf[4];
            for (int mi = 0; mi < 4; ++mi)
                af[mi] = *(const short8*)(As + (wm * 64 + mi * 16 + rl) * 72 + kk + q8);
            for (int ni = 0; ni < 4; ++ni)
                bf[ni] = *(const short8*)(Bs + (wn * 64 + ni * 16 + rl) * 72 + kk + q8);
            for (int mi = 0; mi < 4; ++mi)
                for (int ni = 0; ni < 4; ++ni)
                    acc[mi][ni] = __builtin_amdgcn_mfma_f32_16x16x32_bf16(
                        af[mi], bf[ni], acc[mi][ni], 0, 0, 0);
        }
    }

    int rl = lane & 15, qd = lane >> 4;
    for (int ni = 0; ni < 4; ++ni) {
        int n = n0 + wn * 64 + ni * 16 + rl;
        float bias = bd[n];
        for (int mi = 0; mi < 4; ++mi) {
            for (int r = 0; r < 4; ++r) {
                int m = m0 + wm * 64 + mi * 16 + qd * 4 + r;
                int tt = m >> 5, bb = m & 31;
                out[((size_t)(bb * T_ + tt)) * DV_ + n] = acc[mi][ni][r] + bias;
            }
        }
    }
}

// ---------------------------------------------------------------------------
extern "C" void kernel_launch(void* const* d_in, const int* in_sizes, int n_in,
                              void* d_out, int out_size, void* d_ws, size_t ws_size,
                              hipStream_t stream)
{
    const float* x       = (const float*)d_in[0];
    const float* hidden0 = (const float*)d_in[1];
    const float* cell0   = (const float*)d_in[2];
    const float* enc     = (const float*)d_in[3];
    const float* W1      = (const float*)d_in[4];
    const float* b1      = (const float*)d_in[5];
    const float* W2      = (const float*)d_in[6];
    const float* b2      = (const float*)d_in[7];
    const float* V       = (const float*)d_in[8];
    const float* bV      = (const float*)d_in[9];
    const float* Wx0     = (const float*)d_in[10];
    const float* Wh0     = (const float*)d_in[11];
    const float* bL0     = (const float*)d_in[12];
    const float* Wx1     = (const float*)d_in[13];
    const float* Wh1     = (const float*)d_in[14];
    const float* bL1     = (const float*)d_in[15];
    const float* Wd      = (const float*)d_in[16];
    const float* bd      = (const float*)d_in[17];

    // ---- d_ws layout: byte-identical to the verified-passing baseline.
    char* ws = (char*)d_ws;
    size_t off = 0;
    auto alloc = [&](size_t bytes) -> void* {
        void* ptr = ws + off;
        off = (off + bytes + 255) & ~(size_t)255;
        return ptr;
    };
    unsigned short* WdT = (unsigned short*)alloc((size_t)DV_ * H_ * 2);
    float* encp  = (float*)alloc((size_t)B_ * S_ * A_ * 4);
    float* qg    = (float*)alloc((size_t)B_ * A_ * 4);
    float* p0g   = (float*)alloc((size_t)B_ * H4_ * 4);
    float* p1g   = (float*)alloc((size_t)B_ * H4_ * 4);
    float* ctx   = (float*)alloc((size_t)B_ * H_ * 4);
    float* h0buf = (float*)alloc((size_t)2 * B_ * H_ * 4);
    float* h1buf = (float*)alloc((size_t)2 * B_ * H_ * 4);
    float* c0    = (float*)alloc((size_t)B_ * H_ * 4);
    float* c1    = (float*)alloc((size_t)B_ * H_ * 4);
    unsigned short* h1b = (unsigned short*)alloc((size_t)T_ * B_ * H_ * 2);

    // ---- Transposed weights in the d_out logits region as scratch
    // (20 MB of 262 MB; written before use, overwritten by k_logits last).
    char* sc = (char*)d_out;
    size_t soff = 0;
    auto salloc = [&](size_t bytes) -> void* {
        void* ptr = sc + soff;
        soff = (soff + bytes + 255) & ~(size_t)255;
        return ptr;
    };
    float* WcatT = (float*)salloc((size_t)NCAT_ * H_ * 4);
    float* Wx0T  = (float*)salloc((size_t)H4_ * 768 * 4);
    float* Wx1T  = (float*)salloc((size_t)H4_ * H_ * 4);

    float* out = (float*)d_out;
    float* out_hc = out + (size_t)B_ * T_ * DV_;

    hipLaunchKernelGGL(k_setup, dim3(4100), dim3(256), 0, stream,
                       enc, W2, b2, hidden0, cell0, encp, h0buf, h1buf, c0, c1);
    hipLaunchKernelGGL(k_wdt, dim3(4000), dim3(256), 0, stream, Wd, WdT);
    hipLaunchKernelGGL(k_transpose, dim3(64),  dim3(256), 0, stream, W1,  WcatT,              512, 512);
    hipLaunchKernelGGL(k_transpose, dim3(256), dim3(256), 0, stream, Wh0, WcatT + 512 * 512,  512, 2048);
    hipLaunchKernelGGL(k_transpose, dim3(256), dim3(256), 0, stream, Wh1, WcatT + 2560 * 512, 512, 2048);
    hipLaunchKernelGGL(k_transpose, dim3(384), dim3(256), 0, stream, Wx0, Wx0T,               768, 2048);
    hipLaunchKernelGGL(k_transpose, dim3(256), dim3(256), 0, stream, Wx1, Wx1T,               512, 2048);

    DecodeParams p;
    p.x = x; p.enc = enc;
    p.b1 = b1; p.V = V; p.bV = bV; p.bL0 = bL0; p.bL1 = bL1;
    p.encp = encp; p.WcatT = WcatT; p.Wx0T = Wx0T; p.Wx1T = Wx1T;
    p.qg = qg; p.p0g = p0g; p.p1g = p1g; p.ctx = ctx;
    p.h0buf = h0buf; p.h1buf = h1buf; p.c0 = c0; p.c1 = c1;
    p.h1b = h1b; p.out_hc = out_hc;
    void* args[] = { &p };
    hipError_t cerr = hipLaunchCooperativeKernel((void*)k_decode, dim3(256), dim3(256),
                                                 args, 0, stream);

    if (cerr != hipSuccess) {
        // FALLBACK: per-step normal launches, baseline-verbatim math.
        StepParams sp;
        sp.x = x; sp.enc = enc;
        sp.W1 = W1; sp.b1 = b1; sp.V = V; sp.bV = bV;
        sp.Wx0 = Wx0; sp.Wh0 = Wh0; sp.bL0 = bL0;
        sp.Wx1 = Wx1; sp.Wh1 = Wh1; sp.bL1 = bL1;
        sp.encp = encp;
        sp.qg = qg; sp.p0g = p0g; sp.p1g = p1g; sp.ctx = ctx;
        sp.h0buf = h0buf; sp.h1buf = h1buf; sp.c0 = c0; sp.c1 = c1;
        sp.h1b = h1b;
        for (int t = 0; t < T_; ++t) {
            sp.t = t;
            hipLaunchKernelGGL(kA1_fb, dim3(256), dim3(256), 0, stream, sp);
            hipLaunchKernelGGL(kA2_fb, dim3(32),  dim3(256), 0, stream, sp);
            hipLaunchKernelGGL(kB_fb,  dim3(256), dim3(256), 0, stream, sp);
            hipLaunchKernelGGL(kC_fb,  dim3(256), dim3(256), 0, stream, sp);
        }
        hipLaunchKernelGGL(k_tail_fb, dim3(64), dim3(256), 0, stream,
                           h0buf, h1buf, c0, c1, out_hc);
    }

    hipLaunchKernelGGL(k_logits, dim3(4000), dim3(256), 0, stream, h1b, WdT, bd, out);
}

// Round 5
// 8401.614 us; speedup vs baseline: 2.7181x; 1.9937x over previous
//
#include <hip/hip_runtime.h>
#include <hip/hip_bf16.h>

#define B_  32
#define T_  64
#define S_  64
#define E_  256
#define H_  512
#define A_  512
#define DV_ 32000
#define H4_ 2048
#define NCAT_ 4608   /* W1T(512) + Wh0T(2048) + Wh1T(2048) rows */

typedef __attribute__((ext_vector_type(8))) short short8;
typedef __attribute__((ext_vector_type(4))) float floatx4;

__device__ __forceinline__ float fast_sigmoid(float x) {
    return 1.0f / (1.0f + __expf(-x));
}
__device__ __forceinline__ float fast_tanh(float x) {
    x = fminf(9.0f, fmaxf(-9.0f, x));
    float e = __expf(2.0f * x);
    return (e - 1.0f) / (e + 1.0f);
}
__device__ __forceinline__ unsigned short f2bf(float f) {
    union { float f; unsigned u; } v; v.f = f;
    unsigned r = (v.u + 0x7fffu + ((v.u >> 16) & 1u)) >> 16;
    return (unsigned short)r;
}

// ---------------------------------------------------------------------------
// Setup: enc_proj = encoder_output @ W2 + b2   (blocks 0..4095)
//        state init from hidden0/cell0         (blocks 4096..4099)
// ---------------------------------------------------------------------------
__global__ __launch_bounds__(256) void k_setup(
    const float* __restrict__ enc, const float* __restrict__ W2,
    const float* __restrict__ b2, const float* __restrict__ hidden0,
    const float* __restrict__ cell0,
    float* __restrict__ encp, float* __restrict__ h0buf,
    float* __restrict__ h1buf, float* __restrict__ c0, float* __restrict__ c1)
{
    int bid = blockIdx.x, tid = threadIdx.x;
    if (bid < 4096) {
        int eid = bid * 256 + tid;      // 2048 rows x 512 cols
        int r = eid >> 9;
        int n = eid & 511;
        const float* er = enc + (size_t)r * H_;
        float acc = b2[n];
#pragma unroll 4
        for (int k = 0; k < H_; ++k)
            acc = fmaf(er[k], W2[(size_t)k * A_ + n], acc);
        encp[(size_t)r * A_ + n] = acc;
    } else {
        int which = bid - 4096;  // 0..3
        const float* src = (which == 0) ? hidden0
                         : (which == 1) ? hidden0 + B_ * H_
                         : (which == 2) ? cell0
                         : cell0 + B_ * H_;
        float* dst = (which == 0) ? h0buf : (which == 1) ? h1buf
                   : (which == 2) ? c0 : c1;
        for (int i = tid; i < B_ * H_; i += 256) dst[i] = src[i];
    }
}

// ---------------------------------------------------------------------------
// Wd [512,32000] fp32  ->  WdT [32000,512] bf16 (K-contiguous rows)
// ---------------------------------------------------------------------------
__global__ __launch_bounds__(256) void k_wdt(const float* __restrict__ Wd,
                                             unsigned short* __restrict__ WdT)
{
    __shared__ float tle[64 * 65];
    int kb = blockIdx.x & 7, nb = blockIdx.x >> 3;
    int k0 = kb * 64, n0 = nb * 64;
    int tid = threadIdx.x;
    for (int i = 0; i < 16; ++i) {
        int e = tid + 256 * i;
        int kk = e >> 6, nn = e & 63;
        tle[kk * 65 + nn] = Wd[(size_t)(k0 + kk) * DV_ + n0 + nn];
    }
    __syncthreads();
    for (int i = 0; i < 16; ++i) {
        int e = tid + 256 * i;
        int nn = e >> 6, kk = e & 63;
        WdT[(size_t)(n0 + nn) * H_ + k0 + kk] = f2bf(tle[kk * 65 + nn]);
    }
}

// ---------------------------------------------------------------------------
// Generic fp32 transpose: dst[n*K + k] = src[k*N + n]. K,N multiples of 64.
// ---------------------------------------------------------------------------
__global__ __launch_bounds__(256) void k_transpose(const float* __restrict__ src,
                                                   float* __restrict__ dst,
                                                   int K, int N)
{
    __shared__ float tle[64 * 65];
    int nt = N >> 6;
    int nb = blockIdx.x % nt, kb = blockIdx.x / nt;
    int k0 = kb * 64, n0 = nb * 64;
    int tid = threadIdx.x;
    for (int i = 0; i < 16; ++i) {
        int e = tid + 256 * i;
        int kk = e >> 6, nn = e & 63;
        tle[kk * 65 + nn] = src[(size_t)(k0 + kk) * N + n0 + nn];
    }
    __syncthreads();
    for (int i = 0; i < 16; ++i) {
        int e = tid + 256 * i;
        int nn = e >> 6, kk = e & 63;
        dst[(size_t)(n0 + nn) * K + k0 + kk] = tle[kk * 65 + nn];
    }
}

// ---------------------------------------------------------------------------
// Per-step pipeline. Phase bodies are verbatim from the R4-verified
// cooperative kernel (transposed weights, float4 dots); kernel boundaries
// replace grid.sync, so L2 retains weights and each phase gets a full grid.
// ---------------------------------------------------------------------------
struct StepParams {
    const float *x, *enc;
    const float *b1, *V, *bV, *bL0, *bL1;
    const float *encp;
    const float *WcatT;   // [4608,512]
    const float *Wx0T;    // [2048,768]
    const float *Wx1T;    // [2048,512]
    float *qg, *p0g, *p1g, *ctx;
    float *h0buf, *h1buf, *c0, *c1;
    unsigned short *h1b;
    int t;
};

// A1: q = h1@W1+b1 ; p0 = h0@Wh0 ; p1 = h1@Wh1    grid = 576 (8 cols x 32 b)
__global__ __launch_bounds__(256) void kA1(StepParams p)
{
    int bid = blockIdx.x, tid = threadIdx.x;
    int cur = p.t & 1;
    const float* h0c = p.h0buf + cur * (B_ * H_);
    const float* h1c = p.h1buf + cur * (B_ * H_);
    int b = tid >> 3, nl = tid & 7;
    int n = bid * 8 + nl;                       // 0..4607 (block-uniform region)
    const float* src; float* dst; float bias;
    if (n < 512)       { src = h1c; dst = p.qg  + b * A_  + n;          bias = p.b1[n]; }
    else if (n < 2560) { src = h0c; dst = p.p0g + b * H4_ + (n - 512);  bias = 0.f; }
    else               { src = h1c; dst = p.p1g + b * H4_ + (n - 2560); bias = 0.f; }
    const float4* w4 = (const float4*)(p.WcatT + ((size_t)n << 9));
    const float4* h4 = (const float4*)(src + (b << 9));
    float ax = 0.f, ay = 0.f, az = 0.f, aw = 0.f;
#pragma unroll 8
    for (int kk = 0; kk < 128; ++kk) {
        float4 w = w4[kk], h = h4[kk];
        ax = fmaf(w.x, h.x, ax);
        ay = fmaf(w.y, h.y, ay);
        az = fmaf(w.z, h.z, az);
        aw = fmaf(w.w, h.w, aw);
    }
    *dst = (ax + ay) + (az + aw) + bias;
}

// A2: scores -> softmax -> context    grid = 32 (one block per batch row)
__global__ __launch_bounds__(256) void kA2(StepParams p)
{
    int b = blockIdx.x, tid = threadIdx.x;
    __shared__ float red2[256];
    __shared__ float qs[A_];
    __shared__ float smax[S_];
    qs[tid] = p.qg[b * A_ + tid];
    qs[tid + 256] = p.qg[b * A_ + tid + 256];
    __syncthreads();
    {
        int s = tid >> 2, pp = tid & 3;
        const float* ep = p.encp + ((size_t)(b * S_ + s)) * A_ + pp * 128;
        const float* qq = qs + pp * 128;
        const float* Vv = p.V + pp * 128;
        float acc = 0.f;
#pragma unroll 4
        for (int a = 0; a < 128; ++a)
            acc = fmaf(fast_tanh(ep[a] + qq[a]), Vv[a], acc);
        red2[tid] = acc;
    }
    __syncthreads();
    if (tid < 64) {
        float sv = red2[tid * 4] + red2[tid * 4 + 1] +
                   red2[tid * 4 + 2] + red2[tid * 4 + 3] + p.bV[0];
        float m = sv;
        for (int o = 32; o > 0; o >>= 1) m = fmaxf(m, __shfl_xor(m, o));
        float e = __expf(sv - m);
        float sum = e;
        for (int o = 32; o > 0; o >>= 1) sum += __shfl_xor(sum, o);
        smax[tid] = e / sum;
    }
    __syncthreads();
    {
        float a0 = 0.f, a1 = 0.f;
        for (int s2 = 0; s2 < S_; ++s2) {
            float at = smax[s2];
            const float* er = p.enc + ((size_t)(b * S_ + s2)) * H_;
            a0 = fmaf(at, er[tid], a0);
            a1 = fmaf(at, er[tid + 256], a1);
        }
        p.ctx[b * H_ + tid] = a0;
        p.ctx[b * H_ + tid + 256] = a1;
    }
}

// B: z0 = p0 + ctx@Wx0[:512] + x_t@Wx0[512:768] + bL0 -> h0,c0   grid = 256
__global__ __launch_bounds__(256) void kB(StepParams p)
{
    int bid = blockIdx.x, tid = threadIdx.x;
    int lane = tid & 63;
    int nxt = (p.t & 1) ^ 1;
    float* h0n = p.h0buf + nxt * (B_ * H_);
    int b = tid >> 3, jg = tid & 7;
    int j = bid * 2 + (jg & 1), g = jg >> 1;
    int n = j + (g << 9);
    const float4* w4 = (const float4*)(p.Wx0T + (size_t)n * 768);
    const float4* c4 = (const float4*)(p.ctx + (b << 9));
    const float4* x4 = (const float4*)(p.x + ((size_t)b * T_ + p.t) * E_);
    float ax = 0.f, ay = 0.f, az = 0.f, aw = 0.f;
#pragma unroll 8
    for (int kk = 0; kk < 128; ++kk) {
        float4 w = w4[kk], h = c4[kk];
        ax = fmaf(w.x, h.x, ax);
        ay = fmaf(w.y, h.y, ay);
        az = fmaf(w.z, h.z, az);
        aw = fmaf(w.w, h.w, aw);
    }
#pragma unroll 8
    for (int kk = 0; kk < 64; ++kk) {
        float4 w = w4[128 + kk], h = x4[kk];
        ax = fmaf(w.x, h.x, ax);
        ay = fmaf(w.y, h.y, ay);
        az = fmaf(w.z, h.z, az);
        aw = fmaf(w.w, h.w, aw);
    }
    float acc = p.p0g[b * H4_ + n] + p.bL0[n] + (ax + ay) + (az + aw);
    int lb = lane & ~7, jj = jg & 1;
    float z_f = __shfl(acc, lb + jj + 2);
    float z_g = __shfl(acc, lb + jj + 4);
    float z_o = __shfl(acc, lb + jj + 6);
    if (jg < 2) {
        float ii = fast_sigmoid(acc);
        float ff = fast_sigmoid(z_f);
        float gg = fast_tanh(z_g);
        float oo = fast_sigmoid(z_o);
        float cn = ff * p.c0[b * H_ + j] + ii * gg;
        float hn = oo * fast_tanh(cn);
        p.c0[b * H_ + j] = cn;
        h0n[b * H_ + j] = hn;
    }
}

// C: z1 = p1 + h0_new@Wx1 + bL1 -> h1,c1 ; store h1 as bf16   grid = 256
__global__ __launch_bounds__(256) void kC(StepParams p)
{
    int bid = blockIdx.x, tid = threadIdx.x;
    int lane = tid & 63;
    int nxt = (p.t & 1) ^ 1;
    const float* h0n = p.h0buf + nxt * (B_ * H_);
    float*       h1n = p.h1buf + nxt * (B_ * H_);
    int b = tid >> 3, jg = tid & 7;
    int j = bid * 2 + (jg & 1), g = jg >> 1;
    int n = j + (g << 9);
    const float4* w4 = (const float4*)(p.Wx1T + ((size_t)n << 9));
    const float4* h4 = (const float4*)(h0n + (b << 9));
    float ax = 0.f, ay = 0.f, az = 0.f, aw = 0.f;
#pragma unroll 8
    for (int kk = 0; kk < 128; ++kk) {
        float4 w = w4[kk], h = h4[kk];
        ax = fmaf(w.x, h.x, ax);
        ay = fmaf(w.y, h.y, ay);
        az = fmaf(w.z, h.z, az);
        aw = fmaf(w.w, h.w, aw);
    }
    float acc = p.p1g[b * H4_ + n] + p.bL1[n] + (ax + ay) + (az + aw);
    int lb = lane & ~7, jj = jg & 1;
    float z_f = __shfl(acc, lb + jj + 2);
    float z_g = __shfl(acc, lb + jj + 4);
    float z_o = __shfl(acc, lb + jj + 6);
    if (jg < 2) {
        float ii = fast_sigmoid(acc);
        float ff = fast_sigmoid(z_f);
        float gg = fast_tanh(z_g);
        float oo = fast_sigmoid(z_o);
        float cn = ff * p.c1[b * H_ + j] + ii * gg;
        float hn = oo * fast_tanh(cn);
        p.c1[b * H_ + j] = cn;
        h1n[b * H_ + j] = hn;
        p.h1b[((size_t)p.t * B_ + b) * H_ + j] = f2bf(hn);
    }
}

__global__ __launch_bounds__(256) void k_tail(
    const float* __restrict__ h0buf, const float* __restrict__ h1buf,
    const float* __restrict__ c0, const float* __restrict__ c1,
    float* __restrict__ out_hc)
{
    int idx = blockIdx.x * 256 + threadIdx.x;   // grid 64 -> idx < 16384
    out_hc[idx]               = h0buf[idx];
    out_hc[B_ * H_ + idx]     = h1buf[idx];
    out_hc[2 * B_ * H_ + idx] = c0[idx];
    out_hc[3 * B_ * H_ + idx] = c1[idx];
}

// ---------------------------------------------------------------------------
// Logits: C[m=(t,b), n] = h1b[m,:] . WdT[n,:] + bd[n]  via bf16 MFMA
// ---------------------------------------------------------------------------
__global__ __launch_bounds__(256) void k_logits(
    const unsigned short* __restrict__ Am,   // [2048,512] bf16
    const unsigned short* __restrict__ Bm,   // [32000,512] bf16
    const float* __restrict__ bd,
    float* __restrict__ out)
{
    __shared__ __align__(16) unsigned short As[128 * 72];
    __shared__ __align__(16) unsigned short Bs[128 * 72];
    int tid = threadIdx.x;
    int lane = tid & 63, wv = tid >> 6;
    int mt = blockIdx.x & 15, nt = blockIdx.x >> 4;
    int m0 = mt * 128, n0 = nt * 128;
    int wm = wv >> 1, wn = wv & 1;

    floatx4 acc[4][4];
    for (int i = 0; i < 4; ++i)
        for (int j = 0; j < 4; ++j)
            acc[i][j] = (floatx4){0.f, 0.f, 0.f, 0.f};

    for (int kt = 0; kt < 8; ++kt) {
        int k0 = kt * 64;
        __syncthreads();
        for (int i = 0; i < 4; ++i) {
            int chunk = tid + 256 * i;       // 0..1023
            int row = chunk >> 3, c8 = chunk & 7;
            uint4 va = *(const uint4*)(Am + (size_t)(m0 + row) * H_ + k0 + c8 * 8);
            *(uint4*)(As + row * 72 + c8 * 8) = va;
            uint4 vb = *(const uint4*)(Bm + (size_t)(n0 + row) * H_ + k0 + c8 * 8);
            *(uint4*)(Bs + row * 72 + c8 * 8) = vb;
        }
        __syncthreads();
        int q8 = (lane >> 4) * 8;
        int rl = lane & 15;
        for (int kk = 0; kk < 64; kk += 32) {
            short8 af[4], bf[4];
            for (int mi = 0; mi < 4; ++mi)
                af[mi] = *(const short8*)(As + (wm * 64 + mi * 16 + rl) * 72 + kk + q8);
            for (int ni = 0; ni < 4; ++ni)
                bf[ni] = *(const short8*)(Bs + (wn * 64 + ni * 16 + rl) * 72 + kk + q8);
            for (int mi = 0; mi < 4; ++mi)
                for (int ni = 0; ni < 4; ++ni)
                    acc[mi][ni] = __builtin_amdgcn_mfma_f32_16x16x32_bf16(
                        af[mi], bf[ni], acc[mi][ni], 0, 0, 0);
        }
    }

    int rl = lane & 15, qd = lane >> 4;
    for (int ni = 0; ni < 4; ++ni) {
        int n = n0 + wn * 64 + ni * 16 + rl;
        float bias = bd[n];
        for (int mi = 0; mi < 4; ++mi) {
            for (int r = 0; r < 4; ++r) {
                int m = m0 + wm * 64 + mi * 16 + qd * 4 + r;
                int tt = m >> 5, bb = m & 31;
                out[((size_t)(bb * T_ + tt)) * DV_ + n] = acc[mi][ni][r] + bias;
            }
        }
    }
}

// ---------------------------------------------------------------------------
extern "C" void kernel_launch(void* const* d_in, const int* in_sizes, int n_in,
                              void* d_out, int out_size, void* d_ws, size_t ws_size,
                              hipStream_t stream)
{
    const float* x       = (const float*)d_in[0];
    const float* hidden0 = (const float*)d_in[1];
    const float* cell0   = (const float*)d_in[2];
    const float* enc     = (const float*)d_in[3];
    const float* W1      = (const float*)d_in[4];
    const float* b1      = (const float*)d_in[5];
    const float* W2      = (const float*)d_in[6];
    const float* b2      = (const float*)d_in[7];
    const float* V       = (const float*)d_in[8];
    const float* bV      = (const float*)d_in[9];
    const float* Wx0     = (const float*)d_in[10];
    const float* Wh0     = (const float*)d_in[11];
    const float* bL0     = (const float*)d_in[12];
    const float* Wx1     = (const float*)d_in[13];
    const float* Wh1     = (const float*)d_in[14];
    const float* bL1     = (const float*)d_in[15];
    const float* Wd      = (const float*)d_in[16];
    const float* bd      = (const float*)d_in[17];

    // ---- d_ws layout: byte-identical to the verified-passing baseline.
    char* ws = (char*)d_ws;
    size_t off = 0;
    auto alloc = [&](size_t bytes) -> void* {
        void* ptr = ws + off;
        off = (off + bytes + 255) & ~(size_t)255;
        return ptr;
    };
    unsigned short* WdT = (unsigned short*)alloc((size_t)DV_ * H_ * 2);
    float* encp  = (float*)alloc((size_t)B_ * S_ * A_ * 4);
    float* qg    = (float*)alloc((size_t)B_ * A_ * 4);
    float* p0g   = (float*)alloc((size_t)B_ * H4_ * 4);
    float* p1g   = (float*)alloc((size_t)B_ * H4_ * 4);
    float* ctx   = (float*)alloc((size_t)B_ * H_ * 4);
    float* h0buf = (float*)alloc((size_t)2 * B_ * H_ * 4);
    float* h1buf = (float*)alloc((size_t)2 * B_ * H_ * 4);
    float* c0    = (float*)alloc((size_t)B_ * H_ * 4);
    float* c1    = (float*)alloc((size_t)B_ * H_ * 4);
    unsigned short* h1b = (unsigned short*)alloc((size_t)T_ * B_ * H_ * 2);

    // ---- Transposed weights in the d_out logits region as scratch
    // (20 MB of 262 MB; written before use, overwritten by k_logits last).
    // Verified working placement in R4.
    char* sc = (char*)d_out;
    size_t soff = 0;
    auto salloc = [&](size_t bytes) -> void* {
        void* ptr = sc + soff;
        soff = (soff + bytes + 255) & ~(size_t)255;
        return ptr;
    };
    float* WcatT = (float*)salloc((size_t)NCAT_ * H_ * 4);
    float* Wx0T  = (float*)salloc((size_t)H4_ * 768 * 4);
    float* Wx1T  = (float*)salloc((size_t)H4_ * H_ * 4);

    float* out = (float*)d_out;
    float* out_hc = out + (size_t)B_ * T_ * DV_;

    hipLaunchKernelGGL(k_setup, dim3(4100), dim3(256), 0, stream,
                       enc, W2, b2, hidden0, cell0, encp, h0buf, h1buf, c0, c1);
    hipLaunchKernelGGL(k_wdt, dim3(4000), dim3(256), 0, stream, Wd, WdT);
    hipLaunchKernelGGL(k_transpose, dim3(64),  dim3(256), 0, stream, W1,  WcatT,              512, 512);
    hipLaunchKernelGGL(k_transpose, dim3(256), dim3(256), 0, stream, Wh0, WcatT + 512 * 512,  512, 2048);
    hipLaunchKernelGGL(k_transpose, dim3(256), dim3(256), 0, stream, Wh1, WcatT + 2560 * 512, 512, 2048);
    hipLaunchKernelGGL(k_transpose, dim3(384), dim3(256), 0, stream, Wx0, Wx0T,               768, 2048);
    hipLaunchKernelGGL(k_transpose, dim3(256), dim3(256), 0, stream, Wx1, Wx1T,               512, 2048);

    StepParams sp;
    sp.x = x; sp.enc = enc;
    sp.b1 = b1; sp.V = V; sp.bV = bV; sp.bL0 = bL0; sp.bL1 = bL1;
    sp.encp = encp;
    sp.WcatT = WcatT; sp.Wx0T = Wx0T; sp.Wx1T = Wx1T;
    sp.qg = qg; sp.p0g = p0g; sp.p1g = p1g; sp.ctx = ctx;
    sp.h0buf = h0buf; sp.h1buf = h1buf; sp.c0 = c0; sp.c1 = c1;
    sp.h1b = h1b;

    for (int t = 0; t < T_; ++t) {
        sp.t = t;
        hipLaunchKernelGGL(kA1, dim3(576), dim3(256), 0, stream, sp);
        hipLaunchKernelGGL(kA2, dim3(32),  dim3(256), 0, stream, sp);
        hipLaunchKernelGGL(kB,  dim3(256), dim3(256), 0, stream, sp);
        hipLaunchKernelGGL(kC,  dim3(256), dim3(256), 0, stream, sp);
    }
    hipLaunchKernelGGL(k_tail, dim3(64), dim3(256), 0, stream,
                       h0buf, h1buf, c0, c1, out_hc);

    hipLaunchKernelGGL(k_logits, dim3(4000), dim3(256), 0, stream, h1b, WdT, bd, out);
}

// Round 6
// 7111.572 us; speedup vs baseline: 3.2112x; 1.1814x over previous
//
#include <hip/hip_runtime.h>
#include <hip/hip_bf16.h>

#define B_  32
#define T_  64
#define S_  64
#define E_  256
#define H_  512
#define A_  512
#define DV_ 32000
#define H4_ 2048
#define NCAT_ 4608   /* W1T(512) + Wh0T(2048) + Wh1T(2048) rows */

typedef __attribute__((ext_vector_type(8))) short short8;
typedef __attribute__((ext_vector_type(4))) float floatx4;

__device__ __forceinline__ float fast_sigmoid(float x) {
    return 1.0f / (1.0f + __expf(-x));
}
__device__ __forceinline__ float fast_tanh(float x) {
    x = fminf(9.0f, fmaxf(-9.0f, x));
    float e = __expf(2.0f * x);
    return (e - 1.0f) / (e + 1.0f);
}
__device__ __forceinline__ unsigned short f2bf(float f) {
    union { float f; unsigned u; } v; v.f = f;
    unsigned r = (v.u + 0x7fffu + ((v.u >> 16) & 1u)) >> 16;
    return (unsigned short)r;
}

// ---------------------------------------------------------------------------
// Setup: enc_proj = encoder_output @ W2 + b2   (blocks 0..4095)
//        state init from hidden0/cell0         (blocks 4096..4099)
// ---------------------------------------------------------------------------
__global__ __launch_bounds__(256) void k_setup(
    const float* __restrict__ enc, const float* __restrict__ W2,
    const float* __restrict__ b2, const float* __restrict__ hidden0,
    const float* __restrict__ cell0,
    float* __restrict__ encp, float* __restrict__ h0buf,
    float* __restrict__ h1buf, float* __restrict__ c0, float* __restrict__ c1)
{
    int bid = blockIdx.x, tid = threadIdx.x;
    if (bid < 4096) {
        int eid = bid * 256 + tid;      // 2048 rows x 512 cols
        int r = eid >> 9;
        int n = eid & 511;
        const float* er = enc + (size_t)r * H_;
        float acc = b2[n];
#pragma unroll 4
        for (int k = 0; k < H_; ++k)
            acc = fmaf(er[k], W2[(size_t)k * A_ + n], acc);
        encp[(size_t)r * A_ + n] = acc;
    } else {
        int which = bid - 4096;  // 0..3
        const float* src = (which == 0) ? hidden0
                         : (which == 1) ? hidden0 + B_ * H_
                         : (which == 2) ? cell0
                         : cell0 + B_ * H_;
        float* dst = (which == 0) ? h0buf : (which == 1) ? h1buf
                   : (which == 2) ? c0 : c1;
        for (int i = tid; i < B_ * H_; i += 256) dst[i] = src[i];
    }
}

// ---------------------------------------------------------------------------
// Wd [512,32000] fp32  ->  WdT [32000,512] bf16 (K-contiguous rows)
// ---------------------------------------------------------------------------
__global__ __launch_bounds__(256) void k_wdt(const float* __restrict__ Wd,
                                             unsigned short* __restrict__ WdT)
{
    __shared__ float tle[64 * 65];
    int kb = blockIdx.x & 7, nb = blockIdx.x >> 3;
    int k0 = kb * 64, n0 = nb * 64;
    int tid = threadIdx.x;
    for (int i = 0; i < 16; ++i) {
        int e = tid + 256 * i;
        int kk = e >> 6, nn = e & 63;
        tle[kk * 65 + nn] = Wd[(size_t)(k0 + kk) * DV_ + n0 + nn];
    }
    __syncthreads();
    for (int i = 0; i < 16; ++i) {
        int e = tid + 256 * i;
        int nn = e >> 6, kk = e & 63;
        WdT[(size_t)(n0 + nn) * H_ + k0 + kk] = f2bf(tle[kk * 65 + nn]);
    }
}

// ---------------------------------------------------------------------------
// Generic fp32 transpose: dst[n*K + k] = src[k*N + n]. K,N multiples of 64.
// ---------------------------------------------------------------------------
__global__ __launch_bounds__(256) void k_transpose(const float* __restrict__ src,
                                                   float* __restrict__ dst,
                                                   int K, int N)
{
    __shared__ float tle[64 * 65];
    int nt = N >> 6;
    int nb = blockIdx.x % nt, kb = blockIdx.x / nt;
    int k0 = kb * 64, n0 = nb * 64;
    int tid = threadIdx.x;
    for (int i = 0; i < 16; ++i) {
        int e = tid + 256 * i;
        int kk = e >> 6, nn = e & 63;
        tle[kk * 65 + nn] = src[(size_t)(k0 + kk) * N + n0 + nn];
    }
    __syncthreads();
    for (int i = 0; i < 16; ++i) {
        int e = tid + 256 * i;
        int nn = e >> 6, kk = e & 63;
        dst[(size_t)(n0 + nn) * K + k0 + kk] = tle[kk * 65 + nn];
    }
}

// ---------------------------------------------------------------------------
// encWx0[b][s][n] = sum_{k<512} enc[b][s][k] * Wx0[k][n]  (ctx-part of Wx0)
// grid = 256 blocks: b (32) x s-tile (8 of 8)
// ---------------------------------------------------------------------------
__global__ __launch_bounds__(256) void k_encwx0(const float* __restrict__ enc,
                                                const float* __restrict__ Wx0,
                                                float* __restrict__ out)
{
    __shared__ float er[8][H_];
    int blk = blockIdx.x;
    int b = blk >> 3, st = blk & 7;
    int tid = threadIdx.x;
    for (int i = tid; i < 8 * H_; i += 256) {
        int si = i >> 9, k = i & 511;
        er[si][k] = enc[((size_t)(b * S_ + st * 8 + si)) * H_ + k];
    }
    __syncthreads();
    float acc[8][8];
#pragma unroll
    for (int si = 0; si < 8; ++si)
#pragma unroll
        for (int i = 0; i < 8; ++i) acc[si][i] = 0.f;
    for (int k = 0; k < H_; ++k) {
        const float* wr = Wx0 + (size_t)k * H4_ + tid;
        float w[8];
#pragma unroll
        for (int i = 0; i < 8; ++i) w[i] = wr[i * 256];
#pragma unroll
        for (int si = 0; si < 8; ++si) {
            float e = er[si][k];
#pragma unroll
            for (int i = 0; i < 8; ++i)
                acc[si][i] = fmaf(e, w[i], acc[si][i]);
        }
    }
    for (int si = 0; si < 8; ++si) {
        float* o = out + ((size_t)(b * S_ + st * 8 + si)) * H4_ + tid;
#pragma unroll
        for (int i = 0; i < 8; ++i) o[i * 256] = acc[si][i];
    }
}

// ---------------------------------------------------------------------------
// xproj[b][t][n] = sum_{k<256} x[b][t][k] * Wx0[512+k][n] + bL0[n]
// grid = 256 blocks: b (32) x t-tile (8 of 8)
// ---------------------------------------------------------------------------
__global__ __launch_bounds__(256) void k_xproj(const float* __restrict__ x,
                                               const float* __restrict__ Wx0,
                                               const float* __restrict__ bL0,
                                               float* __restrict__ xproj)
{
    __shared__ float xr[8][E_];
    int blk = blockIdx.x;
    int b = blk >> 3, tt = blk & 7;
    int tid = threadIdx.x;
    for (int i = tid; i < 8 * E_; i += 256) {
        int ti = i >> 8, k = i & 255;
        xr[ti][k] = x[((size_t)b * T_ + tt * 8 + ti) * E_ + k];
    }
    __syncthreads();
    float bl[8];
#pragma unroll
    for (int i = 0; i < 8; ++i) bl[i] = bL0[tid + i * 256];
    float acc[8][8];
#pragma unroll
    for (int si = 0; si < 8; ++si)
#pragma unroll
        for (int i = 0; i < 8; ++i) acc[si][i] = bl[i];
    for (int k = 0; k < E_; ++k) {
        const float* wr = Wx0 + (size_t)(H_ + k) * H4_ + tid;
        float w[8];
#pragma unroll
        for (int i = 0; i < 8; ++i) w[i] = wr[i * 256];
#pragma unroll
        for (int si = 0; si < 8; ++si) {
            float e = xr[si][k];
#pragma unroll
            for (int i = 0; i < 8; ++i)
                acc[si][i] = fmaf(e, w[i], acc[si][i]);
        }
    }
    for (int si = 0; si < 8; ++si) {
        float* o = xproj + ((size_t)b * T_ + tt * 8 + si) * H4_ + tid;
#pragma unroll
        for (int i = 0; i < 8; ++i) o[i * 256] = acc[si][i];
    }
}

// ---------------------------------------------------------------------------
// Per-step pipeline: 3 dispatches/step.
//   kA1  (576 blocks): q,p0,p1   [verbatim from R5-verified]
//   kA2B ( 32 blocks): attn -> z0 = p0 + xproj + attn.encWx0 -> h0,c0 [fold]
//   kC   (256 blocks): h1,c1     [verbatim from R5-verified]
// ---------------------------------------------------------------------------
struct StepParams {
    const float *b1, *V, *bV, *bL1;
    const float *encp;
    const float *WcatT;   // [4608,512]
    const float *Wx1T;    // [2048,512]
    const float *encWx0;  // [B,S,2048]
    const float *xproj;   // [B,T,2048] (includes bL0)
    float *qg, *p0g, *p1g;
    float *h0buf, *h1buf, *c0, *c1;
    unsigned short *h1b;
    int t;
};

// A1: q = h1@W1+b1 ; p0 = h0@Wh0 ; p1 = h1@Wh1    grid = 576
__global__ __launch_bounds__(256) void kA1(StepParams p)
{
    int bid = blockIdx.x, tid = threadIdx.x;
    int cur = p.t & 1;
    const float* h0c = p.h0buf + cur * (B_ * H_);
    const float* h1c = p.h1buf + cur * (B_ * H_);
    int b = tid >> 3, nl = tid & 7;
    int n = bid * 8 + nl;                       // 0..4607 (block-uniform region)
    const float* src; float* dst; float bias;
    if (n < 512)       { src = h1c; dst = p.qg  + b * A_  + n;          bias = p.b1[n]; }
    else if (n < 2560) { src = h0c; dst = p.p0g + b * H4_ + (n - 512);  bias = 0.f; }
    else               { src = h1c; dst = p.p1g + b * H4_ + (n - 2560); bias = 0.f; }
    const float4* w4 = (const float4*)(p.WcatT + ((size_t)n << 9));
    const float4* h4 = (const float4*)(src + (b << 9));
    float ax = 0.f, ay = 0.f, az = 0.f, aw = 0.f;
#pragma unroll 8
    for (int kk = 0; kk < 128; ++kk) {
        float4 w = w4[kk], h = h4[kk];
        ax = fmaf(w.x, h.x, ax);
        ay = fmaf(w.y, h.y, ay);
        az = fmaf(w.z, h.z, az);
        aw = fmaf(w.w, h.w, aw);
    }
    *dst = (ax + ay) + (az + aw) + bias;
}

// A2B: scores -> softmax -> z0 fold -> h0,c0    grid = 32 (one block per b)
__global__ __launch_bounds__(256) void kA2B(StepParams p)
{
    int b = blockIdx.x, tid = threadIdx.x;
    __shared__ float red2[256];
    __shared__ float qs[A_];
    __shared__ float smax[S_];
    qs[tid] = p.qg[b * A_ + tid];
    qs[tid + 256] = p.qg[b * A_ + tid + 256];
    __syncthreads();
    {
        int s = tid >> 2, pp = tid & 3;
        const float* ep = p.encp + ((size_t)(b * S_ + s)) * A_ + pp * 128;
        const float* qq = qs + pp * 128;
        const float* Vv = p.V + pp * 128;
        float acc = 0.f;
#pragma unroll 4
        for (int a = 0; a < 128; ++a)
            acc = fmaf(fast_tanh(ep[a] + qq[a]), Vv[a], acc);
        red2[tid] = acc;
    }
    __syncthreads();
    if (tid < 64) {
        float sv = red2[tid * 4] + red2[tid * 4 + 1] +
                   red2[tid * 4 + 2] + red2[tid * 4 + 3] + p.bV[0];
        float m = sv;
        for (int o = 32; o > 0; o >>= 1) m = fmaxf(m, __shfl_xor(m, o));
        float e = __expf(sv - m);
        float sum = e;
        for (int o = 32; o > 0; o >>= 1) sum += __shfl_xor(sum, o);
        smax[tid] = e / sum;
    }
    __syncthreads();

    // fold-dot: acc8[i] = sum_s attn[s] * encWx0[b][s][tid + i*256]
    float acc8[8];
#pragma unroll
    for (int i = 0; i < 8; ++i) acc8[i] = 0.f;
    const float* ew = p.encWx0 + (size_t)b * (S_ * H4_);
    for (int s = 0; s < S_; ++s) {
        float a = smax[s];
        const float* er = ew + (size_t)s * H4_ + tid;
#pragma unroll
        for (int i = 0; i < 8; ++i)
            acc8[i] = fmaf(a, er[i * 256], acc8[i]);
    }

    // gates in-thread: slot i -> n = tid + i*256 -> (gate g = i>>1... )
    // n layout: i={0,2,4,6} -> j=tid gates i,f,g,o ; i={1,3,5,7} -> j=tid+256
    const float* p0r = p.p0g + b * H4_;
    const float* xpr = p.xproj + ((size_t)b * T_ + p.t) * H4_;
    int nxt = (p.t & 1) ^ 1;
    float* h0n = p.h0buf + nxt * (B_ * H_);
#pragma unroll
    for (int half = 0; half < 2; ++half) {
        int j = tid + half * 256;
        float zi = acc8[half + 0] + p0r[j]        + xpr[j];
        float zf = acc8[half + 2] + p0r[j + 512]  + xpr[j + 512];
        float zg = acc8[half + 4] + p0r[j + 1024] + xpr[j + 1024];
        float zo = acc8[half + 6] + p0r[j + 1536] + xpr[j + 1536];
        float ii = fast_sigmoid(zi);
        float ff = fast_sigmoid(zf);
        float gg = fast_tanh(zg);
        float oo = fast_sigmoid(zo);
        float cn = ff * p.c0[b * H_ + j] + ii * gg;
        float hn = oo * fast_tanh(cn);
        p.c0[b * H_ + j] = cn;
        h0n[b * H_ + j] = hn;
    }
}

// C: z1 = p1 + h0_new@Wx1 + bL1 -> h1,c1 ; store h1 as bf16   grid = 256
__global__ __launch_bounds__(256) void kC(StepParams p)
{
    int bid = blockIdx.x, tid = threadIdx.x;
    int lane = tid & 63;
    int nxt = (p.t & 1) ^ 1;
    const float* h0n = p.h0buf + nxt * (B_ * H_);
    float*       h1n = p.h1buf + nxt * (B_ * H_);
    int b = tid >> 3, jg = tid & 7;
    int j = bid * 2 + (jg & 1), g = jg >> 1;
    int n = j + (g << 9);
    const float4* w4 = (const float4*)(p.Wx1T + ((size_t)n << 9));
    const float4* h4 = (const float4*)(h0n + (b << 9));
    float ax = 0.f, ay = 0.f, az = 0.f, aw = 0.f;
#pragma unroll 8
    for (int kk = 0; kk < 128; ++kk) {
        float4 w = w4[kk], h = h4[kk];
        ax = fmaf(w.x, h.x, ax);
        ay = fmaf(w.y, h.y, ay);
        az = fmaf(w.z, h.z, az);
        aw = fmaf(w.w, h.w, aw);
    }
    float acc = p.p1g[b * H4_ + n] + p.bL1[n] + (ax + ay) + (az + aw);
    int lb = lane & ~7, jj = jg & 1;
    float z_f = __shfl(acc, lb + jj + 2);
    float z_g = __shfl(acc, lb + jj + 4);
    float z_o = __shfl(acc, lb + jj + 6);
    if (jg < 2) {
        float ii = fast_sigmoid(acc);
        float ff = fast_sigmoid(z_f);
        float gg = fast_tanh(z_g);
        float oo = fast_sigmoid(z_o);
        float cn = ff * p.c1[b * H_ + j] + ii * gg;
        float hn = oo * fast_tanh(cn);
        p.c1[b * H_ + j] = cn;
        h1n[b * H_ + j] = hn;
        p.h1b[((size_t)p.t * B_ + b) * H_ + j] = f2bf(hn);
    }
}

__global__ __launch_bounds__(256) void k_tail(
    const float* __restrict__ h0buf, const float* __restrict__ h1buf,
    const float* __restrict__ c0, const float* __restrict__ c1,
    float* __restrict__ out_hc)
{
    int idx = blockIdx.x * 256 + threadIdx.x;   // grid 64 -> idx < 16384
    out_hc[idx]               = h0buf[idx];
    out_hc[B_ * H_ + idx]     = h1buf[idx];
    out_hc[2 * B_ * H_ + idx] = c0[idx];
    out_hc[3 * B_ * H_ + idx] = c1[idx];
}

// ---------------------------------------------------------------------------
// Logits: C[m=(t,b), n] = h1b[m,:] . WdT[n,:] + bd[n]  via bf16 MFMA
// ---------------------------------------------------------------------------
__global__ __launch_bounds__(256) void k_logits(
    const unsigned short* __restrict__ Am,   // [2048,512] bf16
    const unsigned short* __restrict__ Bm,   // [32000,512] bf16
    const float* __restrict__ bd,
    float* __restrict__ out)
{
    __shared__ __align__(16) unsigned short As[128 * 72];
    __shared__ __align__(16) unsigned short Bs[128 * 72];
    int tid = threadIdx.x;
    int lane = tid & 63, wv = tid >> 6;
    int mt = blockIdx.x & 15, nt = blockIdx.x >> 4;
    int m0 = mt * 128, n0 = nt * 128;
    int wm = wv >> 1, wn = wv & 1;

    floatx4 acc[4][4];
    for (int i = 0; i < 4; ++i)
        for (int j = 0; j < 4; ++j)
            acc[i][j] = (floatx4){0.f, 0.f, 0.f, 0.f};

    for (int kt = 0; kt < 8; ++kt) {
        int k0 = kt * 64;
        __syncthreads();
        for (int i = 0; i < 4; ++i) {
            int chunk = tid + 256 * i;       // 0..1023
            int row = chunk >> 3, c8 = chunk & 7;
            uint4 va = *(const uint4*)(Am + (size_t)(m0 + row) * H_ + k0 + c8 * 8);
            *(uint4*)(As + row * 72 + c8 * 8) = va;
            uint4 vb = *(const uint4*)(Bm + (size_t)(n0 + row) * H_ + k0 + c8 * 8);
            *(uint4*)(Bs + row * 72 + c8 * 8) = vb;
        }
        __syncthreads();
        int q8 = (lane >> 4) * 8;
        int rl = lane & 15;
        for (int kk = 0; kk < 64; kk += 32) {
            short8 af[4], bf[4];
            for (int mi = 0; mi < 4; ++mi)
                af[mi] = *(const short8*)(As + (wm * 64 + mi * 16 + rl) * 72 + kk + q8);
            for (int ni = 0; ni < 4; ++ni)
                bf[ni] = *(const short8*)(Bs + (wn * 64 + ni * 16 + rl) * 72 + kk + q8);
            for (int mi = 0; mi < 4; ++mi)
                for (int ni = 0; ni < 4; ++ni)
                    acc[mi][ni] = __builtin_amdgcn_mfma_f32_16x16x32_bf16(
                        af[mi], bf[ni], acc[mi][ni], 0, 0, 0);
        }
    }

    int rl = lane & 15, qd = lane >> 4;
    for (int ni = 0; ni < 4; ++ni) {
        int n = n0 + wn * 64 + ni * 16 + rl;
        float bias = bd[n];
        for (int mi = 0; mi < 4; ++mi) {
            for (int r = 0; r < 4; ++r) {
                int m = m0 + wm * 64 + mi * 16 + qd * 4 + r;
                int tt = m >> 5, bb = m & 31;
                out[((size_t)(bb * T_ + tt)) * DV_ + n] = acc[mi][ni][r] + bias;
            }
        }
    }
}

// ---------------------------------------------------------------------------
extern "C" void kernel_launch(void* const* d_in, const int* in_sizes, int n_in,
                              void* d_out, int out_size, void* d_ws, size_t ws_size,
                              hipStream_t stream)
{
    const float* x       = (const float*)d_in[0];
    const float* hidden0 = (const float*)d_in[1];
    const float* cell0   = (const float*)d_in[2];
    const float* enc     = (const float*)d_in[3];
    const float* W1      = (const float*)d_in[4];
    const float* b1      = (const float*)d_in[5];
    const float* W2      = (const float*)d_in[6];
    const float* b2      = (const float*)d_in[7];
    const float* V       = (const float*)d_in[8];
    const float* bV      = (const float*)d_in[9];
    const float* Wx0     = (const float*)d_in[10];
    const float* Wh0     = (const float*)d_in[11];
    const float* bL0     = (const float*)d_in[12];
    const float* Wx1     = (const float*)d_in[13];
    const float* Wh1     = (const float*)d_in[14];
    const float* bL1     = (const float*)d_in[15];
    const float* Wd      = (const float*)d_in[16];
    const float* bd      = (const float*)d_in[17];

    // ---- d_ws layout: byte-identical to the verified-passing baseline.
    char* ws = (char*)d_ws;
    size_t off = 0;
    auto alloc = [&](size_t bytes) -> void* {
        void* ptr = ws + off;
        off = (off + bytes + 255) & ~(size_t)255;
        return ptr;
    };
    unsigned short* WdT = (unsigned short*)alloc((size_t)DV_ * H_ * 2);
    float* encp  = (float*)alloc((size_t)B_ * S_ * A_ * 4);
    float* qg    = (float*)alloc((size_t)B_ * A_ * 4);
    float* p0g   = (float*)alloc((size_t)B_ * H4_ * 4);
    float* p1g   = (float*)alloc((size_t)B_ * H4_ * 4);
    float* ctx   = (float*)alloc((size_t)B_ * H_ * 4);   (void)ctx;
    float* h0buf = (float*)alloc((size_t)2 * B_ * H_ * 4);
    float* h1buf = (float*)alloc((size_t)2 * B_ * H_ * 4);
    float* c0    = (float*)alloc((size_t)B_ * H_ * 4);
    float* c1    = (float*)alloc((size_t)B_ * H_ * 4);
    unsigned short* h1b = (unsigned short*)alloc((size_t)T_ * B_ * H_ * 2);

    // ---- Big precompute buffers in the d_out logits region as scratch
    // (47 MB of 262 MB; written before decode reads them; k_logits overwrites
    // the region last). This placement is R4/R5-verified.
    char* sc = (char*)d_out;
    size_t soff = 0;
    auto salloc = [&](size_t bytes) -> void* {
        void* ptr = sc + soff;
        soff = (soff + bytes + 255) & ~(size_t)255;
        return ptr;
    };
    float* WcatT  = (float*)salloc((size_t)NCAT_ * H_ * 4);     // 9.44 MB
    float* Wx1T   = (float*)salloc((size_t)H4_ * H_ * 4);       // 4.19 MB
    float* encWx0 = (float*)salloc((size_t)B_ * S_ * H4_ * 4);  // 16.78 MB
    float* xproj  = (float*)salloc((size_t)B_ * T_ * H4_ * 4);  // 16.78 MB

    float* out = (float*)d_out;
    float* out_hc = out + (size_t)B_ * T_ * DV_;

    hipLaunchKernelGGL(k_setup, dim3(4100), dim3(256), 0, stream,
                       enc, W2, b2, hidden0, cell0, encp, h0buf, h1buf, c0, c1);
    hipLaunchKernelGGL(k_wdt, dim3(4000), dim3(256), 0, stream, Wd, WdT);
    hipLaunchKernelGGL(k_transpose, dim3(64),  dim3(256), 0, stream, W1,  WcatT,              512, 512);
    hipLaunchKernelGGL(k_transpose, dim3(256), dim3(256), 0, stream, Wh0, WcatT + 512 * 512,  512, 2048);
    hipLaunchKernelGGL(k_transpose, dim3(256), dim3(256), 0, stream, Wh1, WcatT + 2560 * 512, 512, 2048);
    hipLaunchKernelGGL(k_transpose, dim3(256), dim3(256), 0, stream, Wx1, Wx1T,               512, 2048);
    hipLaunchKernelGGL(k_encwx0, dim3(256), dim3(256), 0, stream, enc, Wx0, encWx0);
    hipLaunchKernelGGL(k_xproj,  dim3(256), dim3(256), 0, stream, x, Wx0, bL0, xproj);

    StepParams sp;
    sp.b1 = b1; sp.V = V; sp.bV = bV; sp.bL1 = bL1;
    sp.encp = encp;
    sp.WcatT = WcatT; sp.Wx1T = Wx1T;
    sp.encWx0 = encWx0; sp.xproj = xproj;
    sp.qg = qg; sp.p0g = p0g; sp.p1g = p1g;
    sp.h0buf = h0buf; sp.h1buf = h1buf; sp.c0 = c0; sp.c1 = c1;
    sp.h1b = h1b;

    for (int t = 0; t < T_; ++t) {
        sp.t = t;
        hipLaunchKernelGGL(kA1,  dim3(576), dim3(256), 0, stream, sp);
        hipLaunchKernelGGL(kA2B, dim3(32),  dim3(256), 0, stream, sp);
        hipLaunchKernelGGL(kC,   dim3(256), dim3(256), 0, stream, sp);
    }
    hipLaunchKernelGGL(k_tail, dim3(64), dim3(256), 0, stream,
                       h0buf, h1buf, c0, c1, out_hc);

    hipLaunchKernelGGL(k_logits, dim3(4000), dim3(256), 0, stream, h1b, WdT, bd, out);
}